// Round 14
// baseline (407.008 us; speedup 1.0000x reference)
//
#include <hip/hip_runtime.h>
#include <hip/hip_bf16.h>

#define IN_DIM   128
#define HIDDEN   256
#define OUT_DIM  128
#define N_NODES  100000
#define N_EDGES  500000
#define N_ROWS   (2 * N_EDGES)   // 1,000,000 rows (2 MC x edges)

typedef __bf16 bf16x8  __attribute__((ext_vector_type(8)));
typedef float  f32x16  __attribute__((ext_vector_type(16)));

// ws layout:
//   [0, 196608)           12 weight chunks x 16384 B, GRANULE-MAJOR (R13):
//                         fragment (k-granule g = k>>3, n) at g*512 + n*16
//                         (+ (k&7)*2). Wave read of frag(s,hi) = s*1024 +
//                         hi*512 + el*16 -> 512 consecutive bytes per
//                         half-wave = ZERO bank conflicts (verified R13).
//                         Chunks 0..7 = W1^T, 8..11 = W2^T.
//   [196608, +51200000)   xbf: x as bf16, row-major [2*N_NODES][128] (256 B rows)
#define XBF_OFF 196608

__global__ void prep_weights(const float* __restrict__ W1,
                             const float* __restrict__ W2,
                             unsigned char* __restrict__ ws) {
  int t = blockIdx.x * 256 + threadIdx.x;
  if (t < HIDDEN * HIDDEN) {           // W1: [k=256][n=256] row-major input
    int n = t & 255, k = t >> 8;
    __bf16 b = (__bf16)W1[k * HIDDEN + n];
    int byte = (n >> 5) * 16384 + (k >> 3) * 512 + (n & 31) * 16 + (k & 7) * 2;
    *reinterpret_cast<__bf16*>(ws + byte) = b;
  } else {
    int t2 = t - HIDDEN * HIDDEN;
    if (t2 < HIDDEN * OUT_DIM) {       // W2: [k=256][n=128]
      int n = t2 & 127, k = t2 >> 7;
      __bf16 b = (__bf16)W2[k * OUT_DIM + n];
      int byte = (8 + (n >> 5)) * 16384 + (k >> 3) * 512 + (n & 31) * 16 + (k & 7) * 2;
      *reinterpret_cast<__bf16*>(ws + byte) = b;
    }
  }
}

// x fp32 -> bf16 table (25.6M elements, 8 per thread, fully coalesced)
__global__ __launch_bounds__(256)
void prep_x(const float* __restrict__ x, unsigned char* __restrict__ xbf) {
  long i = ((long)blockIdx.x * 256 + threadIdx.x) * 8;
  float4 f0 = *reinterpret_cast<const float4*>(x + i);
  float4 f1 = *reinterpret_cast<const float4*>(x + i + 4);
  bf16x8 a;
  a[0] = (__bf16)f0.x; a[1] = (__bf16)f0.y; a[2] = (__bf16)f0.z; a[3] = (__bf16)f0.w;
  a[4] = (__bf16)f1.x; a[5] = (__bf16)f1.y; a[6] = (__bf16)f1.z; a[7] = (__bf16)f1.w;
  *reinterpret_cast<bf16x8*>(xbf + i * 2) = a;
}

static __device__ __forceinline__ unsigned pack_bf16(float a, float b) {
  __bf16 x = (__bf16)a, y = (__bf16)b;
  unsigned short ux = __builtin_bit_cast(unsigned short, x);
  unsigned short uy = __builtin_bit_cast(unsigned short, y);
  return (unsigned)ux | ((unsigned)uy << 16);
}

// L1 epilogue: bias (scalar-load + half-wave select; lgkmcnt path, keeps
// vmcnt counting exact) + relu + pack + permlane transpose.
// C: col=edge=el, row m=(reg&3)+8*(reg>>2)+4*hi -> bias b1c[m].
static __device__ __forceinline__ void h_pack1(const f32x16 acc,
                                               const float* __restrict__ b1c,
                                               int hi, bf16x8& oe, bf16x8& oo) {
  float b[16];
#pragma unroll
  for (int g = 0; g < 4; ++g)
#pragma unroll
    for (int r = 0; r < 4; ++r)
      b[g * 4 + r] = hi ? b1c[g * 8 + 4 + r] : b1c[g * 8 + r];  // s_load + cndmask
  unsigned w0 = pack_bf16(fmaxf(acc[0]  + b[0],  0.f), fmaxf(acc[1]  + b[1],  0.f));
  unsigned w1 = pack_bf16(fmaxf(acc[2]  + b[2],  0.f), fmaxf(acc[3]  + b[3],  0.f));
  unsigned w2 = pack_bf16(fmaxf(acc[4]  + b[4],  0.f), fmaxf(acc[5]  + b[5],  0.f));
  unsigned w3 = pack_bf16(fmaxf(acc[6]  + b[6],  0.f), fmaxf(acc[7]  + b[7],  0.f));
  unsigned w4 = pack_bf16(fmaxf(acc[8]  + b[8],  0.f), fmaxf(acc[9]  + b[9],  0.f));
  unsigned w5 = pack_bf16(fmaxf(acc[10] + b[10], 0.f), fmaxf(acc[11] + b[11], 0.f));
  unsigned w6 = pack_bf16(fmaxf(acc[12] + b[12], 0.f), fmaxf(acc[13] + b[13], 0.f));
  unsigned w7 = pack_bf16(fmaxf(acc[14] + b[14], 0.f), fmaxf(acc[15] + b[15], 0.f));
  // half-wave exchange: vdst' = (a.row0, b.row0); vsrc' = (a.row1, b.row1)
  asm("v_permlane32_swap_b32 %0, %1" : "+v"(w0), "+v"(w2));
  asm("v_permlane32_swap_b32 %0, %1" : "+v"(w1), "+v"(w3));
  asm("v_permlane32_swap_b32 %0, %1" : "+v"(w4), "+v"(w6));
  asm("v_permlane32_swap_b32 %0, %1" : "+v"(w5), "+v"(w7));
  uint4 fe; fe.x = w0; fe.y = w1; fe.z = w2; fe.w = w3;
  uint4 fo; fo.x = w4; fo.y = w5; fo.z = w6; fo.w = w7;
  oe = __builtin_bit_cast(bf16x8, fe);
  oo = __builtin_bit_cast(bf16x8, fo);
}

// R13 base (granule-major conflict-free LDS, bf16 x-table gather) + R11's
// counted-vmcnt double-buffer skeleton, register-lean this time:
// R11's failure was occupancy collapse (VGPR 132 tipped unified VGPR+AGPR
// past 256/wave -> 1 wave/SIMD); R13 base is 84 VGPR, and bias now goes
// through the SCALAR path (s_load+cndmask for b1; 4 preloaded floats for b2)
// instead of R11's onefrag/bfr MFMA machinery. 12 phases, 2x16KB dbuf
// (same 32 KB LDS), wait constants re-derived = R11's proven 8/24/16:
// each wave waits only its OWN 8 staging loads; chunk t+1's stay in flight
// across the barriers; no vmcnt(0) drain anywhere in the loop.
// NOTE: do NOT use 256-thread variants — R5 miscompiled (absmax 1.75).
// NOTE: do NOT cap min-waves — R4 spilled ~900 MB.
__global__ __launch_bounds__(128)
void edge_mlp(const int* __restrict__ eidx,
              const unsigned char* __restrict__ xbf,
              const float* __restrict__ b1,
              const float* __restrict__ b2,
              const unsigned char* __restrict__ ws,
              float* __restrict__ out) {
  __shared__ __align__(16) unsigned char wbuf[2][16384];

  const int tid  = threadIdx.x;
  const int wv   = tid >> 6;           // wave 0..1
  const int lane = tid & 63;
  const int el   = lane & 31;          // edge within wave tile
  const int hi   = lane >> 5;          // k half

  const long base = (long)blockIdx.x * 64;
  const long gr   = base + wv * 32 + el;
  const int  mc   = (gr >= N_EDGES) ? 1 : 0;
  const int  e    = (int)(gr - (long)mc * N_EDGES);
  const int  sn   = eidx[e];
  const int  dn   = eidx[N_EDGES + e];
  const unsigned char* xsb = xbf + ((long)mc * N_NODES + sn) * 256;
  const unsigned char* xdb = xbf + ((long)mc * N_NODES + dn) * 256;

  // ---- prologue VMEM: b2 per-lane values + x fragments (retire before
  //      the loop's first wait; fence pins them BEFORE the staging loads) ----
  float b2v[4];
#pragma unroll
  for (int c = 0; c < 4; ++c) b2v[c] = b2[c * 32 + el];

  bf16x8 a1[16];
#pragma unroll
  for (int s = 0; s < 16; ++s) {
    const unsigned char* p = (s < 8) ? (xsb + s * 32 + hi * 16)
                                     : (xdb + (s - 8) * 32 + hi * 16);
    a1[s] = *reinterpret_cast<const bf16x8*>(p);
  }
  asm volatile("" ::: "memory");       // pin: gathers/b2 older than staging

  // one 16 KB chunk -> dbuf slot b; 8 sweeps of 2048 B = 8 loads per wave
#define STAGE(t, b)                                                            \
  do {                                                                         \
    const unsigned char* g_ = ws + (t) * 16384;                                \
    _Pragma("unroll")                                                          \
    for (int i_ = 0; i_ < 8; ++i_) {                                           \
      __builtin_amdgcn_global_load_lds(                                        \
          (const __attribute__((address_space(1))) unsigned int*)(g_ + i_ * 2048 + tid * 16), \
          (__attribute__((address_space(3))) unsigned int*)(&wbuf[b][i_ * 2048 + tid * 16]),  \
          16, 0, 0);                                                           \
    }                                                                          \
  } while (0)

  STAGE(0, 0);
  asm volatile("" ::: "memory");       // pin: S0 older than S1
  STAGE(1, 1);
  asm volatile("" ::: "memory");

  // per-lane fragment offset within a chunk: frag(s,hi) = s*1024 + hi*512 + el*16
  const int fo0 = hi * 512 + el * 16;
  bf16x8 a2[16];

  // ---- 12 phases, counted-vmcnt pipeline (never vmcnt(0) in the loop) ----
#pragma unroll
  for (int t = 0; t < 12; ++t) {
    // chunk t's 8 staging loads (this wave's share) must have landed;
    // chunk t+1's 8 stay in flight. Stores enter the count for t>=9.
    if (t <= 8)       asm volatile("s_waitcnt vmcnt(8)"  ::: "memory");
    else if (t <= 10) asm volatile("s_waitcnt vmcnt(24)" ::: "memory");
    else              asm volatile("s_waitcnt vmcnt(16)" ::: "memory");
    __builtin_amdgcn_s_barrier();      // publish both waves' halves
    asm volatile("" ::: "memory");

    const unsigned char* wb = wbuf[t & 1] + fo0;

    if (t < 8) {
      // layer 1 (swapped): D[hcol][edge] = W1^T x ; E/O dual chains
      f32x16 aE = {}, aO = {};
#pragma unroll
      for (int ks = 0; ks < 8; ++ks) {
        bf16x8 wE = *reinterpret_cast<const bf16x8*>(wb + (2 * ks) * 1024);
        bf16x8 wO = *reinterpret_cast<const bf16x8*>(wb + (2 * ks + 1) * 1024);
        aE = __builtin_amdgcn_mfma_f32_32x32x16_bf16(wE, a1[2 * ks],     aE, 0, 0, 0);
        aO = __builtin_amdgcn_mfma_f32_32x32x16_bf16(wO, a1[2 * ks + 1], aO, 0, 0, 0);
      }
      f32x16 acc = aE + aO;
      h_pack1(acc, b1 + t * 32, hi, a2[2 * t], a2[2 * t + 1]);
    } else {
      // layer 2 (standard): out[edge][ocol] = h W2 + b2
      const int u = t - 8;
      f32x16 aE = {}, aO = {};
#pragma unroll
      for (int ks = 0; ks < 8; ++ks) {
        bf16x8 wE = *reinterpret_cast<const bf16x8*>(wb + (2 * ks) * 1024);
        bf16x8 wO = *reinterpret_cast<const bf16x8*>(wb + (2 * ks + 1) * 1024);
        aE = __builtin_amdgcn_mfma_f32_32x32x16_bf16(a2[2 * ks],     wE, aE, 0, 0, 0);
        aO = __builtin_amdgcn_mfma_f32_32x32x16_bf16(a2[2 * ks + 1], wO, aO, 0, 0, 0);
      }
      f32x16 acc = aE + aO;
      const long r0 = base + wv * 32;
#pragma unroll
      for (int reg = 0; reg < 16; ++reg) {
        int m = (reg & 3) + 8 * (reg >> 2) + 4 * hi;
        out[(r0 + m) * OUT_DIM + u * 32 + el] = acc[reg] + b2v[u];
      }
    }

    asm volatile("" ::: "memory");
    __builtin_amdgcn_s_barrier();      // all waves done reading buf[t&1]
    asm volatile("" ::: "memory");
    if (t + 2 < 12) STAGE(t + 2, t & 1);
  }
#undef STAGE
}

extern "C" void kernel_launch(void* const* d_in, const int* in_sizes, int n_in,
                              void* d_out, int out_size, void* d_ws, size_t ws_size,
                              hipStream_t stream) {
  const int*   eidx = (const int*)d_in[0];
  const float* x    = (const float*)d_in[1];
  const float* b1   = (const float*)d_in[3];
  const float* b2   = (const float*)d_in[5];
  float* out = (float*)d_out;
  unsigned char* ws = (unsigned char*)d_ws;

  prep_weights<<<(HIDDEN * HIDDEN + HIDDEN * OUT_DIM) / 256, 256, 0, stream>>>(
      (const float*)d_in[2], (const float*)d_in[4], ws);

  // x -> bf16 table: 25.6M elements, 8/thread -> 12500 blocks exactly
  prep_x<<<12500, 256, 0, stream>>>(x, ws + XBF_OFF);

  // 64 rows per block, exact grid (no tail)
  edge_mlp<<<N_ROWS / 64, 128, 0, stream>>>(eidx, ws + XBF_OFF, b1, b2, ws, out);
  (void)in_sizes; (void)n_in; (void)out_size; (void)ws_size;
}

// Round 15
// 333.436 us; speedup vs baseline: 1.2206x; 1.2206x over previous
//
#include <hip/hip_runtime.h>
#include <hip/hip_bf16.h>

#define IN_DIM   128
#define HIDDEN   256
#define OUT_DIM  128
#define N_NODES  100000
#define N_EDGES  500000
#define N_ROWS   (2 * N_EDGES)   // 1,000,000 rows (2 MC x edges)

typedef __bf16 bf16x8  __attribute__((ext_vector_type(8)));
typedef float  f32x16  __attribute__((ext_vector_type(16)));

// ws layout:
//   [0, 196608)           12 weight chunks x 16384 B (32 n-cols x 512 B, K=256
//                         bf16, XOR-swizzled by ((n&7)<<4) in 16B granules;
//                         chunks 0..7 = W1^T, 8..11 = W2^T)
//   [196608, +51200000)   xbf: x as bf16, row-major [2*N_NODES][128] (256 B rows)
//
// R15 = R10 VERBATIM (session best: 326 us). R11/R14 proved counted-vmcnt
// collapses occupancy at this register pressure (VGPR 132/144 -> 1 wave/SIMD);
// R12 free-run geometry 360; R13 conflict-free layout 342. R10 is the
// measured optimum of this dataflow.
#define W1S_OFF 0
#define W2S_OFF 131072
#define XBF_OFF 196608

__global__ void prep_weights(const float* __restrict__ W1,
                             const float* __restrict__ W2,
                             unsigned char* __restrict__ ws) {
  int t = blockIdx.x * 256 + threadIdx.x;
  if (t < HIDDEN * HIDDEN) {           // W1: [k=256][n=256] row-major input
    int n = t & 255, k = t >> 8;
    __bf16 b = (__bf16)W1[k * HIDDEN + n];
    int byte = W1S_OFF + n * 512 + ((k * 2) ^ ((n & 7) << 4));
    *reinterpret_cast<__bf16*>(ws + byte) = b;
  } else {
    int t2 = t - HIDDEN * HIDDEN;
    if (t2 < HIDDEN * OUT_DIM) {       // W2: [k=256][n=128]
      int n = t2 & 127, k = t2 >> 7;
      __bf16 b = (__bf16)W2[k * OUT_DIM + n];
      int byte = W2S_OFF + n * 512 + ((k * 2) ^ ((n & 7) << 4));
      *reinterpret_cast<__bf16*>(ws + byte) = b;
    }
  }
}

// x fp32 -> bf16 table (25.6M elements, 8 per thread, fully coalesced)
__global__ __launch_bounds__(256)
void prep_x(const float* __restrict__ x, unsigned char* __restrict__ xbf) {
  long i = ((long)blockIdx.x * 256 + threadIdx.x) * 8;
  float4 f0 = *reinterpret_cast<const float4*>(x + i);
  float4 f1 = *reinterpret_cast<const float4*>(x + i + 4);
  bf16x8 a;
  a[0] = (__bf16)f0.x; a[1] = (__bf16)f0.y; a[2] = (__bf16)f0.z; a[3] = (__bf16)f0.w;
  a[4] = (__bf16)f1.x; a[5] = (__bf16)f1.y; a[6] = (__bf16)f1.z; a[7] = (__bf16)f1.w;
  *reinterpret_cast<bf16x8*>(xbf + i * 2) = a;
}

static __device__ __forceinline__ unsigned pack_bf16(float a, float b) {
  __bf16 x = (__bf16)a, y = (__bf16)b;
  unsigned short ux = __builtin_bit_cast(unsigned short, x);
  unsigned short uy = __builtin_bit_cast(unsigned short, y);
  return (unsigned)ux | ((unsigned)uy << 16);
}

// L1 epilogue: bias+relu+pack+register-transpose (proven R3/R6/R9/R10).
// C: col=edge=el, row m=(reg&3)+8*(reg>>2)+4*hi.
static __device__ __forceinline__ void h_pack(const f32x16 acc,
                                              const float* __restrict__ b1c,
                                              int hi, bf16x8& oe, bf16x8& oo) {
  float4 bv0 = *reinterpret_cast<const float4*>(b1c + hi * 4);
  float4 bv1 = *reinterpret_cast<const float4*>(b1c + 8 + hi * 4);
  float4 bv2 = *reinterpret_cast<const float4*>(b1c + 16 + hi * 4);
  float4 bv3 = *reinterpret_cast<const float4*>(b1c + 24 + hi * 4);
  unsigned w0 = pack_bf16(fmaxf(acc[0] + bv0.x, 0.f),  fmaxf(acc[1] + bv0.y, 0.f));
  unsigned w1 = pack_bf16(fmaxf(acc[2] + bv0.z, 0.f),  fmaxf(acc[3] + bv0.w, 0.f));
  unsigned w2 = pack_bf16(fmaxf(acc[4] + bv1.x, 0.f),  fmaxf(acc[5] + bv1.y, 0.f));
  unsigned w3 = pack_bf16(fmaxf(acc[6] + bv1.z, 0.f),  fmaxf(acc[7] + bv1.w, 0.f));
  unsigned w4 = pack_bf16(fmaxf(acc[8] + bv2.x, 0.f),  fmaxf(acc[9] + bv2.y, 0.f));
  unsigned w5 = pack_bf16(fmaxf(acc[10] + bv2.z, 0.f), fmaxf(acc[11] + bv2.w, 0.f));
  unsigned w6 = pack_bf16(fmaxf(acc[12] + bv3.x, 0.f), fmaxf(acc[13] + bv3.y, 0.f));
  unsigned w7 = pack_bf16(fmaxf(acc[14] + bv3.z, 0.f), fmaxf(acc[15] + bv3.w, 0.f));
  // half-wave exchange: vdst' = (a.row0, b.row0); vsrc' = (a.row1, b.row1)
  asm("v_permlane32_swap_b32 %0, %1" : "+v"(w0), "+v"(w2));
  asm("v_permlane32_swap_b32 %0, %1" : "+v"(w1), "+v"(w3));
  asm("v_permlane32_swap_b32 %0, %1" : "+v"(w4), "+v"(w6));
  asm("v_permlane32_swap_b32 %0, %1" : "+v"(w5), "+v"(w7));
  uint4 fe; fe.x = w0; fe.y = w1; fe.z = w2; fe.w = w3;
  uint4 fo; fo.x = w4; fo.y = w5; fo.z = w6; fo.w = w7;
  oe = __builtin_bit_cast(bf16x8, fe);
  oo = __builtin_bit_cast(bf16x8, fo);
}

// 128 threads = 2 waves x 32 edges. Swapped L1 mfma(W,x) + permlane transpose
// (proven R3/R6/R9/R10). Chunk-paired staging (R9). Gather reads the bf16
// table: the 256 B bf16 row layout IS the fragment layout -> 16 direct 16 B
// loads, zero conversion VALU, half the fabric bytes.
// NOTE: do NOT use 256-thread variants — R5 miscompiled (absmax 1.75).
// NOTE: do NOT cap min-waves — R4 spilled ~900 MB (live set ~160+ VGPR).
// NOTE: do NOT use counted-vmcnt dbuf here — R11/R14: VGPR 132/144 -> 11% occ.
__global__ __launch_bounds__(128)
void edge_mlp(const int* __restrict__ eidx,
              const unsigned char* __restrict__ xbf,
              const float* __restrict__ b1,
              const float* __restrict__ b2,
              const unsigned char* __restrict__ ws,
              float* __restrict__ out) {
  __shared__ __align__(16) unsigned char wbuf[32768];   // 2 chunks

  const int tid  = threadIdx.x;
  const int wv   = tid >> 6;           // wave 0..1
  const int lane = tid & 63;
  const int el   = lane & 31;          // edge within wave tile
  const int hi   = lane >> 5;          // k half

  const long base = (long)blockIdx.x * 64;
  const long gr   = base + wv * 32 + el;
  const int  mc   = (gr >= N_EDGES) ? 1 : 0;
  const int  e    = (int)(gr - (long)mc * N_EDGES);
  const int  sn   = eidx[e];
  const int  dn   = eidx[N_EDGES + e];
  const unsigned char* xsb = xbf + ((long)mc * N_NODES + sn) * 256;
  const unsigned char* xdb = xbf + ((long)mc * N_NODES + dn) * 256;

  // ---- x fragments (B of swapped L1, 32x32x16): lane holds edge=el,
  //      k = s*16 + hi*8 + j -> bf16 row byte s*32 + hi*16, 16 B direct ----
  bf16x8 a1[16];
#pragma unroll
  for (int s = 0; s < 16; ++s) {
    const unsigned char* p = (s < 8) ? (xsb + s * 32 + hi * 16)
                                     : (xdb + (s - 8) * 32 + hi * 16);
    a1[s] = *reinterpret_cast<const bf16x8*>(p);
  }

  // 128 threads copy TWO chunks (32768 B) in 16 sweeps of 2048 B
#define STAGE2(t)                                                              \
  do {                                                                         \
    const unsigned char* g_ = ws + (t) * 16384;                                \
    _Pragma("unroll")                                                          \
    for (int i_ = 0; i_ < 16; ++i_) {                                          \
      __builtin_amdgcn_global_load_lds(                                        \
          (const __attribute__((address_space(1))) unsigned int*)(g_ + i_ * 2048 + tid * 16), \
          (__attribute__((address_space(3))) unsigned int*)(&wbuf[i_ * 2048 + tid * 16]),     \
          16, 0, 0);                                                           \
    }                                                                          \
  } while (0)

  const int rowb = el * 512;
  const int swz  = (el & 7) << 4;

  bf16x8 a2[16];

  // ---- layer 1 (swapped): 4 phases x 2 chunks; D[hcol][edge] = W1^T x ----
#pragma unroll
  for (int p = 0; p < 4; ++p) {
    const int c0 = 2 * p;
    __syncthreads();                    // previous phase's readers done
    STAGE2(c0);
    __syncthreads();                    // stage drained (vmcnt0 + barrier)
    f32x16 aA = {}, aB = {};
#pragma unroll
    for (int ks = 0; ks < 16; ++ks) {
      const int off = rowb + ((ks * 32 + hi * 16) ^ swz);
      bf16x8 wfA = *reinterpret_cast<const bf16x8*>(&wbuf[off]);
      bf16x8 wfB = *reinterpret_cast<const bf16x8*>(&wbuf[16384 + off]);
      aA = __builtin_amdgcn_mfma_f32_32x32x16_bf16(wfA, a1[ks], aA, 0, 0, 0);
      aB = __builtin_amdgcn_mfma_f32_32x32x16_bf16(wfB, a1[ks], aB, 0, 0, 0);
    }
    h_pack(aA, b1 + c0 * 32,      hi, a2[2 * c0],     a2[2 * c0 + 1]);
    h_pack(aB, b1 + c0 * 32 + 32, hi, a2[2 * c0 + 2], a2[2 * c0 + 3]);
  }

  // ---- layer 2 (standard): 2 phases x 2 chunks; out = h @ W2 + b2 ----
#pragma unroll
  for (int q = 0; q < 2; ++q) {
    const int oc0 = 2 * q;
    __syncthreads();
    STAGE2(8 + oc0);
    __syncthreads();
    f32x16 aA = {}, aB = {};
#pragma unroll
    for (int kk = 0; kk < 16; ++kk) {
      const int off = rowb + ((kk * 32 + hi * 16) ^ swz);
      bf16x8 wfA = *reinterpret_cast<const bf16x8*>(&wbuf[off]);
      bf16x8 wfB = *reinterpret_cast<const bf16x8*>(&wbuf[16384 + off]);
      aA = __builtin_amdgcn_mfma_f32_32x32x16_bf16(a2[kk], wfA, aA, 0, 0, 0);
      aB = __builtin_amdgcn_mfma_f32_32x32x16_bf16(a2[kk], wfB, aB, 0, 0, 0);
    }
    const long r0 = base + wv * 32;
    float bvA = b2[oc0 * 32 + el];
    float bvB = b2[oc0 * 32 + 32 + el];
#pragma unroll
    for (int reg = 0; reg < 16; ++reg) {
      int m = (reg & 3) + 8 * (reg >> 2) + 4 * hi;
      out[(r0 + m) * OUT_DIM + oc0 * 32 + el]      = aA[reg] + bvA;
      out[(r0 + m) * OUT_DIM + oc0 * 32 + 32 + el] = aB[reg] + bvB;
    }
  }
#undef STAGE2
}

extern "C" void kernel_launch(void* const* d_in, const int* in_sizes, int n_in,
                              void* d_out, int out_size, void* d_ws, size_t ws_size,
                              hipStream_t stream) {
  const int*   eidx = (const int*)d_in[0];
  const float* x    = (const float*)d_in[1];
  const float* b1   = (const float*)d_in[3];
  const float* b2   = (const float*)d_in[5];
  float* out = (float*)d_out;
  unsigned char* ws = (unsigned char*)d_ws;

  prep_weights<<<(HIDDEN * HIDDEN + HIDDEN * OUT_DIM) / 256, 256, 0, stream>>>(
      (const float*)d_in[2], (const float*)d_in[4], ws);

  // x -> bf16 table: 25.6M elements, 8/thread -> 12500 blocks exactly
  prep_x<<<12500, 256, 0, stream>>>(x, ws + XBF_OFF);

  // 64 rows per block, exact grid (no tail)
  edge_mlp<<<N_ROWS / 64, 128, 0, stream>>>(eidx, ws + XBF_OFF, b1, b2, ws, out);
  (void)in_sizes; (void)n_in; (void)out_size; (void)ws_size;
}